// Round 1
// baseline (1146.130 us; speedup 1.0000x reference)
//
#include <hip/hip_runtime.h>

typedef _Float16 f16;
typedef _Float16 f16x8 __attribute__((ext_vector_type(8)));
typedef _Float16 f16x4 __attribute__((ext_vector_type(4)));
typedef float f32x4 __attribute__((ext_vector_type(4)));
typedef float fv4 __attribute__((ext_vector_type(4)));

#define BN_EPS 1e-5f

constexpr int EPI_RAW = 0;        // write fp32 C (no transform)        [sim]
constexpr int EPI_HILO_NORM = 1;  // BN+ReLU -> hi/lo fp16 + row norm2  [Q,K]
constexpr int EPI_HALF_NORM = 2;  // BN+ReLU -> fp16 + row norm2        [V]
constexpr int EPI_HALF = 3;       // fp16 C (no transform)              [wv]
constexpr int EPI_BN_F32 = 4;     // BN+ReLU -> fp32 C                  [f]

__device__ __forceinline__ void gload_lds16(const void* g, void* l) {
  __builtin_amdgcn_global_load_lds(
      (const __attribute__((address_space(1))) unsigned int*)g,
      (__attribute__((address_space(3))) unsigned int*)l, 16, 0, 0);
}

// ---------------------------------------------------------------- GEMM
// C[M,N] = A[M,K] * B[N,K]^T   (both row-major, lda=ldb=K, ldc=N)
// NPASS==3: A,B given as (hi,lo) fp16 pairs; computes Ah*Bh + Ah*Bl + Al*Bh.
// 2x2 waves, wave tile (BM/2)x(BN/2), 16x16x32 f16 MFMA, BK=32.
template <int BM, int BN, int NPASS, int EPI>
__global__ __launch_bounds__(256, 2) void gemm_kernel(
    const f16* __restrict__ Ah, const f16* __restrict__ Al,
    const f16* __restrict__ Bh, const f16* __restrict__ Bl, int M, int N,
    int K, long long sAb, long long sBb, long long sCb,
    float* __restrict__ Cf, f16* __restrict__ Ch, f16* __restrict__ Cl,
    const float* __restrict__ bias, const float* __restrict__ gamma,
    const float* __restrict__ beta, const float* __restrict__ mean,
    const float* __restrict__ var, float* __restrict__ norm2) {
  (void)M;
  constexpr int BK = 32;
  constexpr int WM = BM / 2, WN = BN / 2;
  constexpr int FM = WM / 16, FN = WN / 16;
  constexpr int NT = (NPASS == 3) ? 2 : 1;

  __shared__ __align__(16) f16 lds[NT * (BM + BN) * BK];
  f16* sA = lds;
  f16* sB = lds + BM * BK;
  f16* sA2 = lds + (BM + BN) * BK;  // only used when NPASS==3
  f16* sB2 = sA2 + BM * BK;

  const int b = blockIdx.z;
  const f16* pA = Ah + (size_t)b * sAb;
  const f16* pB = Bh + (size_t)b * sBb;
  const f16* pA2 = (NPASS == 3) ? Al + (size_t)b * sAb : (const f16*)nullptr;
  const f16* pB2 = (NPASS == 3) ? Bl + (size_t)b * sBb : (const f16*)nullptr;

  const int brow = blockIdx.y * BM, bcol = blockIdx.x * BN;
  const int t = threadIdx.x, wave = t >> 6, lane = t & 63;
  const int wr = wave >> 1, wc = wave & 1;

  f32x4 acc[FM][FN] = {};

  constexpr int A_CH = BM / 16, B_CH = BN / 16;
  constexpr int TOT = NT * (A_CH + B_CH);  // all instantiations: TOT % 4 == 0

  const int srow = lane >> 2;         // 0..15 row within 16-row chunk
  const int scol = (lane & 3) * 8;    // halves offset within row
  const int lr = lane & 15;
  const int lkb = (lane >> 4) * 8;    // frag k offset (halves)

  for (int k0 = 0; k0 < K; k0 += BK) {
    for (int id = wave; id < TOT; id += 4) {
      const f16* g;
      f16* l;
      if (id < A_CH) {
        int c = id;
        g = pA + (size_t)(brow + c * 16 + srow) * K + k0 + scol;
        l = sA + c * 16 * BK;
      } else if (id < A_CH + B_CH) {
        int c = id - A_CH;
        g = pB + (size_t)(bcol + c * 16 + srow) * K + k0 + scol;
        l = sB + c * 16 * BK;
      } else if (id < 2 * A_CH + B_CH) {
        int c = id - (A_CH + B_CH);
        g = pA2 + (size_t)(brow + c * 16 + srow) * K + k0 + scol;
        l = sA2 + c * 16 * BK;
      } else {
        int c = id - (2 * A_CH + B_CH);
        g = pB2 + (size_t)(bcol + c * 16 + srow) * K + k0 + scol;
        l = sB2 + c * 16 * BK;
      }
      gload_lds16(g, l);
    }
    asm volatile("s_waitcnt vmcnt(0)" ::: "memory");
    __syncthreads();

    f16x8 fa[FM], fb[FN];
#pragma unroll
    for (int mi = 0; mi < FM; ++mi)
      fa[mi] = *(const f16x8*)(sA + (size_t)(wr * WM + mi * 16 + lr) * BK + lkb);
#pragma unroll
    for (int ni = 0; ni < FN; ++ni)
      fb[ni] = *(const f16x8*)(sB + (size_t)(wc * WN + ni * 16 + lr) * BK + lkb);
#pragma unroll
    for (int mi = 0; mi < FM; ++mi)
#pragma unroll
      for (int ni = 0; ni < FN; ++ni)
        acc[mi][ni] = __builtin_amdgcn_mfma_f32_16x16x32_f16(fa[mi], fb[ni],
                                                             acc[mi][ni], 0, 0, 0);
    if constexpr (NPASS == 3) {
      f16x8 fa2[FM], fb2[FN];
#pragma unroll
      for (int mi = 0; mi < FM; ++mi)
        fa2[mi] =
            *(const f16x8*)(sA2 + (size_t)(wr * WM + mi * 16 + lr) * BK + lkb);
#pragma unroll
      for (int ni = 0; ni < FN; ++ni)
        fb2[ni] =
            *(const f16x8*)(sB2 + (size_t)(wc * WN + ni * 16 + lr) * BK + lkb);
#pragma unroll
      for (int mi = 0; mi < FM; ++mi)
#pragma unroll
        for (int ni = 0; ni < FN; ++ni) {
          acc[mi][ni] = __builtin_amdgcn_mfma_f32_16x16x32_f16(
              fa[mi], fb2[ni], acc[mi][ni], 0, 0, 0);
          acc[mi][ni] = __builtin_amdgcn_mfma_f32_16x16x32_f16(
              fa2[mi], fb[ni], acc[mi][ni], 0, 0, 0);
        }
    }
    __syncthreads();
  }

  // epilogue; C/D layout: col = lane&15, row = (lane>>4)*4 + j
#pragma unroll
  for (int mi = 0; mi < FM; ++mi) {
#pragma unroll
    for (int j = 0; j < 4; ++j) {
      const int grow = brow + wr * WM + mi * 16 + (lane >> 4) * 4 + j;
      float nsum = 0.0f;
#pragma unroll
      for (int ni = 0; ni < FN; ++ni) {
        const int gcol = bcol + wc * WN + ni * 16 + lr;
        float val = acc[mi][ni][j];
        if constexpr (EPI == EPI_RAW) {
          Cf[(size_t)b * sCb + (size_t)grow * N + gcol] = val;
        } else if constexpr (EPI == EPI_HALF) {
          Ch[(size_t)b * sCb + (size_t)grow * N + gcol] = (f16)val;
        } else {
          float y = fmaxf(val + bias[gcol], 0.0f);
          y = gamma[gcol] * (y - mean[gcol]) / sqrtf(var[gcol] + BN_EPS) +
              beta[gcol];
          if constexpr (EPI == EPI_BN_F32) {
            Cf[(size_t)grow * N + gcol] = y;
          } else if constexpr (EPI == EPI_HALF_NORM) {
            Ch[(size_t)grow * N + gcol] = (f16)y;
            nsum += y * y;
          } else {  // EPI_HILO_NORM
            f16 h = (f16)y;
            Ch[(size_t)grow * N + gcol] = h;
            Cl[(size_t)grow * N + gcol] = (f16)(y - (float)h);
            nsum += y * y;
          }
        }
      }
      if constexpr (EPI == EPI_HILO_NORM || EPI == EPI_HALF_NORM) {
        nsum += __shfl_xor(nsum, 1);
        nsum += __shfl_xor(nsum, 2);
        nsum += __shfl_xor(nsum, 4);
        nsum += __shfl_xor(nsum, 8);
        if (lr == 0) atomicAdd(&norm2[grow], nsum);
      }
    }
  }
}

// ---------------------------------------------------------------- helpers
__global__ __launch_bounds__(256) void cvt_hilo_kernel(
    const float* __restrict__ in, f16* __restrict__ hi, f16* __restrict__ lo,
    int n4) {
  int i = blockIdx.x * 256 + threadIdx.x;
  if (i >= n4) return;
  fv4 v = ((const fv4*)in)[i];
  f16x4 h, l;
#pragma unroll
  for (int j = 0; j < 4; ++j) {
    f16 hh = (f16)v[j];
    h[j] = hh;
    l[j] = (f16)(v[j] - (float)hh);
  }
  ((f16x4*)hi)[i] = h;
  ((f16x4*)lo)[i] = l;
}

__global__ __launch_bounds__(256) void cvt_hi_kernel(const float* __restrict__ in,
                                                     f16* __restrict__ hi,
                                                     int n4) {
  int i = blockIdx.x * 256 + threadIdx.x;
  if (i >= n4) return;
  fv4 v = ((const fv4*)in)[i];
  f16x4 h;
#pragma unroll
  for (int j = 0; j < 4; ++j) h[j] = (f16)v[j];
  ((f16x4*)hi)[i] = h;
}

// mean over trailing 7x7=49; one block per (b,n)
__global__ __launch_bounds__(256) void pool_kernel(const float* __restrict__ x,
                                                   f16* __restrict__ ah,
                                                   f16* __restrict__ al) {
  int bn = blockIdx.x;
  const float* base = x + (size_t)bn * 1024 * 49;
  for (int d = threadIdx.x; d < 1024; d += 256) {
    const float* p = base + (size_t)d * 49;
    float s = 0.f;
#pragma unroll
    for (int j = 0; j < 49; ++j) s += p[j];
    float m = s / 49.0f;
    f16 h = (f16)m;
    ah[(size_t)bn * 1024 + d] = h;
    al[(size_t)bn * 1024 + d] = (f16)(m - (float)h);
  }
}

// 2048x2048 fp16 transpose per batch, 64x64 tiles
__global__ __launch_bounds__(256) void transpose_kernel(
    const f16* __restrict__ in, f16* __restrict__ out) {
  __shared__ __align__(16) f16 tile[64][72];
  int b = blockIdx.z;
  const f16* src = in + (size_t)b * 2048 * 2048;
  f16* dst = out + (size_t)b * 2048 * 2048;
  int r0 = blockIdx.y * 64, c0 = blockIdx.x * 64;
  int t = threadIdx.x;
  for (int i = t; i < 512; i += 256) {
    int r = i >> 3, c8 = (i & 7) * 8;
    f16x8 v = *(const f16x8*)(src + (size_t)(r0 + r) * 2048 + c0 + c8);
    *(f16x8*)&tile[r][c8] = v;
  }
  __syncthreads();
  for (int i = t; i < 512; i += 256) {
    int r = i >> 3, c8 = (i & 7) * 8;
    f16x8 v;
#pragma unroll
    for (int j = 0; j < 8; ++j) v[j] = tile[c8 + j][r];
    *(f16x8*)(dst + (size_t)(c0 + r) * 2048 + r0 + c8) = v;
  }
}

// one block per (b,n) row: scale by 100/(|q||k|), mask, softmax, fold 1/|v|
__global__ __launch_bounds__(256) void softmax_kernel(
    const float* __restrict__ raw, const float* __restrict__ qn2,
    const float* __restrict__ kn2, const float* __restrict__ vn2,
    const int* __restrict__ nvalid, f16* __restrict__ wgt) {
  const int n = blockIdx.x;  // 64
  const int b = blockIdx.y;  // 8
  const int row = b * 64 + n;
  const float* r = raw + (size_t)row * 2048;
  const int nv = nvalid[b];
  const float qs = 100.0f / fmaxf(sqrtf(qn2[row]), 1e-12f);

  __shared__ float sl[2048];
  __shared__ float red[4];
  const int t = threadIdx.x;

  float mx = -3.0e38f;
  for (int m = t; m < 2048; m += 256) {
    float v = -3.0e38f;
    if (m < nv) {
      float ks = 1.0f / fmaxf(sqrtf(kn2[b * 2048 + m]), 1e-12f);
      v = r[m] * qs * ks;
    }
    sl[m] = v;
    mx = fmaxf(mx, v);
  }
#pragma unroll
  for (int s = 32; s; s >>= 1) mx = fmaxf(mx, __shfl_xor(mx, s));
  if ((t & 63) == 0) red[t >> 6] = mx;
  __syncthreads();
  mx = fmaxf(fmaxf(red[0], red[1]), fmaxf(red[2], red[3]));
  __syncthreads();

  float sum = 0.f;
  for (int m = t; m < 2048; m += 256) {
    float e = (m < nv) ? __expf(sl[m] - mx) : 0.0f;
    sl[m] = e;
    sum += e;
  }
#pragma unroll
  for (int s = 32; s; s >>= 1) sum += __shfl_xor(sum, s);
  if ((t & 63) == 0) red[t >> 6] = sum;
  __syncthreads();
  sum = red[0] + red[1] + red[2] + red[3];
  const float inv = 1.0f / sum;

  for (int m = t; m < 2048; m += 256) {
    float vs = 1.0f / fmaxf(sqrtf(vn2[b * 2048 + m]), 1e-12f);
    wgt[(size_t)row * 2048 + m] = (f16)(sl[m] * inv * vs);
  }
}

// out = x + f_context[bnd] broadcast over the 49 spatial positions
__global__ __launch_bounds__(256) void add_kernel(const float* __restrict__ x,
                                                  const float* __restrict__ fc,
                                                  float* __restrict__ out,
                                                  int n4) {
  int i = blockIdx.x * 256 + threadIdx.x;
  if (i >= n4) return;
  fv4 v = ((const fv4*)x)[i];
  int e = i * 4;
#pragma unroll
  for (int j = 0; j < 4; ++j) v[j] += fc[(e + j) / 49];
  ((fv4*)out)[i] = v;
}

// ---------------------------------------------------------------- launch
extern "C" void kernel_launch(void* const* d_in, const int* in_sizes, int n_in,
                              void* d_out, int out_size, void* d_ws,
                              size_t ws_size, hipStream_t stream) {
  (void)in_sizes; (void)n_in; (void)out_size; (void)ws_size;
  const float* x = (const float*)d_in[0];
  const float* xc = (const float*)d_in[1];
  const int* nvp = (const int*)d_in[2];
  const float* qW = (const float*)d_in[3];
  const float* qB = (const float*)d_in[4];
  const float* qG = (const float*)d_in[5];
  const float* qBe = (const float*)d_in[6];
  const float* qM = (const float*)d_in[7];
  const float* qV = (const float*)d_in[8];
  const float* kW = (const float*)d_in[9];
  const float* kB = (const float*)d_in[10];
  const float* kG = (const float*)d_in[11];
  const float* kBe = (const float*)d_in[12];
  const float* kM = (const float*)d_in[13];
  const float* kV = (const float*)d_in[14];
  const float* vW = (const float*)d_in[15];
  const float* vB = (const float*)d_in[16];
  const float* vG = (const float*)d_in[17];
  const float* vBe = (const float*)d_in[18];
  const float* vM = (const float*)d_in[19];
  const float* vV = (const float*)d_in[20];
  const float* fW = (const float*)d_in[21];
  const float* fB = (const float*)d_in[22];
  const float* fG = (const float*)d_in[23];
  const float* fBe = (const float*)d_in[24];
  const float* fM = (const float*)d_in[25];
  const float* fV = (const float*)d_in[26];
  float* out = (float*)d_out;

  const int NRq = 512;    // B*n
  const int NRc = 16384;  // B*m
  const int Dd = 1024, Cc = 2048, D1 = 2048, D2 = 2048, Mm = 2048;

  char* p = (char*)d_ws;
  auto take = [&](size_t bytes) -> char* {
    char* r = p;
    p += (bytes + 255) & ~(size_t)255;
    return r;
  };
  f16* xch = (f16*)take((size_t)NRc * Cc * 2);
  f16* xcl = (f16*)take((size_t)NRc * Cc * 2);
  f16* kh = (f16*)take((size_t)NRc * D1 * 2);
  f16* kl = (f16*)take((size_t)NRc * D1 * 2);
  f16* vh = (f16*)take((size_t)NRc * D2 * 2);
  f16* qWh = (f16*)take((size_t)D1 * Dd * 2);
  f16* qWl = (f16*)take((size_t)D1 * Dd * 2);
  f16* kWh = (f16*)take((size_t)D1 * Cc * 2);
  f16* kWl = (f16*)take((size_t)D1 * Cc * 2);
  f16* vWh = (f16*)take((size_t)D2 * Cc * 2);
  f16* fWh = (f16*)take((size_t)Dd * D2 * 2);
  f16* Aph = (f16*)take((size_t)NRq * Dd * 2);
  f16* Apl = (f16*)take((size_t)NRq * Dd * 2);
  f16* qh = (f16*)take((size_t)NRq * D1 * 2);
  f16* ql = (f16*)take((size_t)NRq * D1 * 2);
  float* qn2 = (float*)take((size_t)NRq * 4);
  float* kn2 = (float*)take((size_t)NRc * 4);
  float* vn2 = (float*)take((size_t)NRc * 4);
  float* raw = (float*)take((size_t)NRq * Mm * 4);
  f16* wgt = (f16*)take((size_t)NRq * Mm * 2);
  f16* wvh = (f16*)take((size_t)NRq * D2 * 2);
  float* fctx = (float*)take((size_t)NRq * Dd * 4);
  f16* vT = xch;  // alias: x_context hi no longer needed after V GEMM

  // conversions to fp16 hi/lo
  cvt_hilo_kernel<<<dim3((NRc * Cc / 4 + 255) / 256), 256, 0, stream>>>(
      xc, xch, xcl, NRc * Cc / 4);
  cvt_hilo_kernel<<<dim3((D1 * Dd / 4 + 255) / 256), 256, 0, stream>>>(
      qW, qWh, qWl, D1 * Dd / 4);
  cvt_hilo_kernel<<<dim3((D1 * Cc / 4 + 255) / 256), 256, 0, stream>>>(
      kW, kWh, kWl, D1 * Cc / 4);
  cvt_hi_kernel<<<dim3((D2 * Cc / 4 + 255) / 256), 256, 0, stream>>>(
      vW, vWh, D2 * Cc / 4);
  cvt_hi_kernel<<<dim3((Dd * D2 / 4 + 255) / 256), 256, 0, stream>>>(
      fW, fWh, Dd * D2 / 4);
  pool_kernel<<<dim3(512), 256, 0, stream>>>(x, Aph, Apl);

  hipMemsetAsync(qn2, 0, (size_t)NRq * 4, stream);
  hipMemsetAsync(kn2, 0, (size_t)NRc * 4, stream);
  hipMemsetAsync(vn2, 0, (size_t)NRc * 4, stream);

  // Q: [512,1024] x [2048,1024]^T -> BN/ReLU -> hi/lo + norm2
  gemm_kernel<128, 128, 3, EPI_HILO_NORM>
      <<<dim3(D1 / 128, NRq / 128, 1), 256, 0, stream>>>(
          Aph, Apl, qWh, qWl, NRq, D1, Dd, 0, 0, 0, nullptr, qh, ql, qB, qG,
          qBe, qM, qV, qn2);
  // K: [16384,2048] x [2048,2048]^T
  gemm_kernel<128, 128, 3, EPI_HILO_NORM>
      <<<dim3(D1 / 128, NRc / 128, 1), 256, 0, stream>>>(
          xch, xcl, kWh, kWl, NRc, D1, Cc, 0, 0, 0, nullptr, kh, kl, kB, kG,
          kBe, kM, kV, kn2);
  // V: single-pass fp16
  gemm_kernel<128, 128, 1, EPI_HALF_NORM>
      <<<dim3(D2 / 128, NRc / 128, 1), 256, 0, stream>>>(
          xch, nullptr, vWh, nullptr, NRc, D2, Cc, 0, 0, 0, nullptr, vh,
          nullptr, vB, vG, vBe, vM, vV, vn2);
  // values -> values^T per batch (for wv GEMM B-operand)
  transpose_kernel<<<dim3(32, 32, 8), 256, 0, stream>>>(vh, vT);
  // sim (batched): q[64,2048] x k[2048,2048]^T -> raw fp32
  gemm_kernel<64, 128, 3, EPI_RAW><<<dim3(Mm / 128, 1, 8), 256, 0, stream>>>(
      qh, ql, kh, kl, 64, Mm, D1, (long long)64 * D1, (long long)Mm * D1,
      (long long)64 * Mm, raw, nullptr, nullptr, nullptr, nullptr, nullptr,
      nullptr, nullptr, nullptr);
  softmax_kernel<<<dim3(64, 8), 256, 0, stream>>>(raw, qn2, kn2, vn2, nvp, wgt);
  // wv (batched): wgt[64,2048] x vT[2048,2048]^T -> fp16
  gemm_kernel<64, 128, 1, EPI_HALF><<<dim3(D2 / 128, 1, 8), 256, 0, stream>>>(
      wgt, nullptr, vT, nullptr, 64, D2, Mm, (long long)64 * Mm,
      (long long)D2 * Mm, (long long)64 * D2, nullptr, wvh, nullptr, nullptr,
      nullptr, nullptr, nullptr, nullptr, nullptr);
  // f: [512,2048] x [1024,2048]^T -> BN/ReLU -> fp32
  gemm_kernel<128, 128, 1, EPI_BN_F32>
      <<<dim3(Dd / 128, NRq / 128, 1), 256, 0, stream>>>(
          wvh, nullptr, fWh, nullptr, NRq, Dd, D2, 0, 0, 0, fctx, nullptr,
          nullptr, fB, fG, fBe, fM, fV, nullptr);
  // out = x + f_context broadcast
  add_kernel<<<dim3(25690112 / 4 / 256), 256, 0, stream>>>(x, fctx, out,
                                                           25690112 / 4);
}

// Round 2
// 974.003 us; speedup vs baseline: 1.1767x; 1.1767x over previous
//
#include <hip/hip_runtime.h>

typedef _Float16 f16;
typedef _Float16 f16x8 __attribute__((ext_vector_type(8)));
typedef _Float16 f16x4 __attribute__((ext_vector_type(4)));
typedef float f32x4 __attribute__((ext_vector_type(4)));
typedef float fv4 __attribute__((ext_vector_type(4)));

#define BN_EPS 1e-5f

constexpr int EPI_RAW = 0;        // write fp32 C (no transform)        [sim]
constexpr int EPI_HILO_NORM = 1;  // BN+ReLU -> hi/lo fp16 + row norm2  [Q,K]
constexpr int EPI_HALF_NORM = 2;  // BN+ReLU -> fp16 + row norm2        [V]
constexpr int EPI_HALF = 3;       // fp16 C (no transform)              [wv]
constexpr int EPI_BN_F32 = 4;     // BN+ReLU -> fp32 C                  [f]

__device__ __forceinline__ void gload_lds16(const void* g, void* l) {
  __builtin_amdgcn_global_load_lds(
      (const __attribute__((address_space(1))) unsigned int*)g,
      (__attribute__((address_space(3))) unsigned int*)l, 16, 0, 0);
}

// ---------------------------------------------------------------- GEMM
// C[M,N] = A[M,K] * B[N,K]^T   (both row-major, lda=ldb=K, ldc=N)
// A has AP fp16 parts (hi[,lo]), B has BP parts. Computes the sum of
// A_ai * B_bi over all (ai,bi) with ai+bi <= 1 (i.e. 1/2/3-pass splits).
// 2x2 waves, wave tile (BM/2)x(BN/2), 16x16x32 f16 MFMA, BK=32.
template <int BM, int BN, int AP, int BP, int EPI>
__global__ __launch_bounds__(256, 2) void gemm_kernel(
    const f16* __restrict__ Ah, const f16* __restrict__ Al,
    const f16* __restrict__ Bh, const f16* __restrict__ Bl, int M, int N,
    int K, long long sAb, long long sBb, long long sCb,
    float* __restrict__ Cf, f16* __restrict__ Ch, f16* __restrict__ Cl,
    const float* __restrict__ bias, const float* __restrict__ gamma,
    const float* __restrict__ beta, const float* __restrict__ mean,
    const float* __restrict__ var, float* __restrict__ norm2) {
  (void)M;
  constexpr int BK = 32;
  constexpr int WM = BM / 2, WN = BN / 2;
  constexpr int FM = WM / 16, FN = WN / 16;

  __shared__ __align__(16) f16 lds[(AP * BM + BP * BN) * BK];
  f16* sA = lds;                    // part ap at sA + ap*BM*BK
  f16* sB = lds + AP * BM * BK;     // part bp at sB + bp*BN*BK

  const int b = blockIdx.z;
  const f16* pA = Ah + (size_t)b * sAb;
  const f16* pB = Bh + (size_t)b * sBb;
  const f16* pA2 = (AP == 2) ? Al + (size_t)b * sAb : (const f16*)nullptr;
  const f16* pB2 = (BP == 2) ? Bl + (size_t)b * sBb : (const f16*)nullptr;

  const int brow = blockIdx.y * BM, bcol = blockIdx.x * BN;
  const int t = threadIdx.x, wave = t >> 6, lane = t & 63;
  const int wr = wave >> 1, wc = wave & 1;

  f32x4 acc[FM][FN] = {};

  constexpr int A_CH = BM / 16, B_CH = BN / 16;
  constexpr int TOT = AP * A_CH + BP * B_CH;  // all instantiations: TOT%4==0

  const int srow = lane >> 2;       // 0..15 row within 16-row chunk
  const int scol = (lane & 3) * 8;  // halves offset within row
  const int lr = lane & 15;
  const int lkb = (lane >> 4) * 8;  // frag k offset (halves)

  for (int k0 = 0; k0 < K; k0 += BK) {
    for (int id = wave; id < TOT; id += 4) {
      const f16* g;
      f16* l;
      if (id < AP * A_CH) {
        const f16* src = pA;
        f16* dst = sA;
        int c = id;
        if constexpr (AP == 2) {
          if (id >= A_CH) {
            src = pA2;
            dst = sA + BM * BK;
            c = id - A_CH;
          }
        }
        g = src + (size_t)(brow + c * 16 + srow) * K + k0 + scol;
        l = dst + c * 16 * BK;
      } else {
        int j = id - AP * A_CH;
        const f16* src = pB;
        f16* dst = sB;
        int c = j;
        if constexpr (BP == 2) {
          if (j >= B_CH) {
            src = pB2;
            dst = sB + BN * BK;
            c = j - B_CH;
          }
        }
        g = src + (size_t)(bcol + c * 16 + srow) * K + k0 + scol;
        l = dst + c * 16 * BK;
      }
      gload_lds16(g, l);
    }
    asm volatile("s_waitcnt vmcnt(0)" ::: "memory");
    __syncthreads();

    f16x8 fa[AP][FM], fb[BP][FN];
#pragma unroll
    for (int ap = 0; ap < AP; ++ap)
#pragma unroll
      for (int mi = 0; mi < FM; ++mi)
        fa[ap][mi] = *(const f16x8*)(sA + ap * BM * BK +
                                     (size_t)(wr * WM + mi * 16 + lr) * BK + lkb);
#pragma unroll
    for (int bp = 0; bp < BP; ++bp)
#pragma unroll
      for (int ni = 0; ni < FN; ++ni)
        fb[bp][ni] = *(const f16x8*)(sB + bp * BN * BK +
                                     (size_t)(wc * WN + ni * 16 + lr) * BK + lkb);
#pragma unroll
    for (int ap = 0; ap < AP; ++ap)
#pragma unroll
      for (int bp = 0; bp < BP; ++bp) {
        if (ap + bp >= 2) continue;
#pragma unroll
        for (int mi = 0; mi < FM; ++mi)
#pragma unroll
          for (int ni = 0; ni < FN; ++ni)
            acc[mi][ni] = __builtin_amdgcn_mfma_f32_16x16x32_f16(
                fa[ap][mi], fb[bp][ni], acc[mi][ni], 0, 0, 0);
      }
    __syncthreads();
  }

  // epilogue; C/D layout: col = lane&15, row = (lane>>4)*4 + j
#pragma unroll
  for (int mi = 0; mi < FM; ++mi) {
#pragma unroll
    for (int j = 0; j < 4; ++j) {
      const int grow = brow + wr * WM + mi * 16 + (lane >> 4) * 4 + j;
      float nsum = 0.0f;
#pragma unroll
      for (int ni = 0; ni < FN; ++ni) {
        const int gcol = bcol + wc * WN + ni * 16 + lr;
        float val = acc[mi][ni][j];
        if constexpr (EPI == EPI_RAW) {
          Cf[(size_t)b * sCb + (size_t)grow * N + gcol] = val;
        } else if constexpr (EPI == EPI_HALF) {
          Ch[(size_t)b * sCb + (size_t)grow * N + gcol] = (f16)val;
        } else {
          float y = fmaxf(val + bias[gcol], 0.0f);
          y = gamma[gcol] * (y - mean[gcol]) / sqrtf(var[gcol] + BN_EPS) +
              beta[gcol];
          if constexpr (EPI == EPI_BN_F32) {
            Cf[(size_t)grow * N + gcol] = y;
          } else if constexpr (EPI == EPI_HALF_NORM) {
            Ch[(size_t)grow * N + gcol] = (f16)y;
            nsum += y * y;
          } else {  // EPI_HILO_NORM
            f16 h = (f16)y;
            Ch[(size_t)grow * N + gcol] = h;
            Cl[(size_t)grow * N + gcol] = (f16)(y - (float)h);
            nsum += y * y;
          }
        }
      }
      if constexpr (EPI == EPI_HILO_NORM || EPI == EPI_HALF_NORM) {
        nsum += __shfl_xor(nsum, 1);
        nsum += __shfl_xor(nsum, 2);
        nsum += __shfl_xor(nsum, 4);
        nsum += __shfl_xor(nsum, 8);
        if (lr == 0) atomicAdd(&norm2[grow], nsum);
      }
    }
  }
}

// ---------------------------------------------------------------- helpers
__global__ __launch_bounds__(256) void cvt_hilo_kernel(
    const float* __restrict__ in, f16* __restrict__ hi, f16* __restrict__ lo,
    int n4) {
  int i = blockIdx.x * 256 + threadIdx.x;
  if (i >= n4) return;
  fv4 v = ((const fv4*)in)[i];
  f16x4 h, l;
#pragma unroll
  for (int j = 0; j < 4; ++j) {
    f16 hh = (f16)v[j];
    h[j] = hh;
    l[j] = (f16)(v[j] - (float)hh);
  }
  ((f16x4*)hi)[i] = h;
  ((f16x4*)lo)[i] = l;
}

__global__ __launch_bounds__(256) void cvt_hi_kernel(const float* __restrict__ in,
                                                     f16* __restrict__ hi,
                                                     int n4) {
  int i = blockIdx.x * 256 + threadIdx.x;
  if (i >= n4) return;
  fv4 v = ((const fv4*)in)[i];
  f16x4 h;
#pragma unroll
  for (int j = 0; j < 4; ++j) h[j] = (f16)v[j];
  ((f16x4*)hi)[i] = h;
}

// mean over trailing 7x7=49; one block per (b,n)
__global__ __launch_bounds__(256) void pool_kernel(const float* __restrict__ x,
                                                   f16* __restrict__ ah) {
  int bn = blockIdx.x;
  const float* base = x + (size_t)bn * 1024 * 49;
  for (int d = threadIdx.x; d < 1024; d += 256) {
    const float* p = base + (size_t)d * 49;
    float s = 0.f;
#pragma unroll
    for (int j = 0; j < 49; ++j) s += p[j];
    ah[(size_t)bn * 1024 + d] = (f16)(s / 49.0f);
  }
}

// 2048x2048 fp16 transpose per batch, 64x64 tiles
__global__ __launch_bounds__(256) void transpose_kernel(
    const f16* __restrict__ in, f16* __restrict__ out) {
  __shared__ __align__(16) f16 tile[64][72];
  int b = blockIdx.z;
  const f16* src = in + (size_t)b * 2048 * 2048;
  f16* dst = out + (size_t)b * 2048 * 2048;
  int r0 = blockIdx.y * 64, c0 = blockIdx.x * 64;
  int t = threadIdx.x;
  for (int i = t; i < 512; i += 256) {
    int r = i >> 3, c8 = (i & 7) * 8;
    f16x8 v = *(const f16x8*)(src + (size_t)(r0 + r) * 2048 + c0 + c8);
    *(f16x8*)&tile[r][c8] = v;
  }
  __syncthreads();
  for (int i = t; i < 512; i += 256) {
    int r = i >> 3, c8 = (i & 7) * 8;
    f16x8 v;
#pragma unroll
    for (int j = 0; j < 8; ++j) v[j] = tile[c8 + j][r];
    *(f16x8*)(dst + (size_t)(c0 + r) * 2048 + r0 + c8) = v;
  }
}

// one block per (b,n) row: scale by 100/(|q||k|), mask, softmax, fold 1/|v|
__global__ __launch_bounds__(256) void softmax_kernel(
    const float* __restrict__ raw, const float* __restrict__ qn2,
    const float* __restrict__ kn2, const float* __restrict__ vn2,
    const int* __restrict__ nvalid, f16* __restrict__ wgt) {
  const int n = blockIdx.x;  // 64
  const int b = blockIdx.y;  // 8
  const int row = b * 64 + n;
  const float* r = raw + (size_t)row * 2048;
  const int nv = nvalid[b];
  const float qs = 100.0f / fmaxf(sqrtf(qn2[row]), 1e-12f);

  __shared__ float sl[2048];
  __shared__ float red[4];
  const int t = threadIdx.x;

  float mx = -3.0e38f;
  for (int m = t; m < 2048; m += 256) {
    float v = -3.0e38f;
    if (m < nv) {
      float ks = 1.0f / fmaxf(sqrtf(kn2[b * 2048 + m]), 1e-12f);
      v = r[m] * qs * ks;
    }
    sl[m] = v;
    mx = fmaxf(mx, v);
  }
#pragma unroll
  for (int s = 32; s; s >>= 1) mx = fmaxf(mx, __shfl_xor(mx, s));
  if ((t & 63) == 0) red[t >> 6] = mx;
  __syncthreads();
  mx = fmaxf(fmaxf(red[0], red[1]), fmaxf(red[2], red[3]));
  __syncthreads();

  float sum = 0.f;
  for (int m = t; m < 2048; m += 256) {
    float e = (m < nv) ? __expf(sl[m] - mx) : 0.0f;
    sl[m] = e;
    sum += e;
  }
#pragma unroll
  for (int s = 32; s; s >>= 1) sum += __shfl_xor(sum, s);
  if ((t & 63) == 0) red[t >> 6] = sum;
  __syncthreads();
  sum = red[0] + red[1] + red[2] + red[3];
  const float inv = 1.0f / sum;

  for (int m = t; m < 2048; m += 256) {
    float vs = 1.0f / fmaxf(sqrtf(vn2[b * 2048 + m]), 1e-12f);
    wgt[(size_t)row * 2048 + m] = (f16)(sl[m] * inv * vs);
  }
}

// out = x + f_context[bnd] broadcast over the 49 spatial positions
__global__ __launch_bounds__(256) void add_kernel(const float* __restrict__ x,
                                                  const float* __restrict__ fc,
                                                  float* __restrict__ out,
                                                  int n4) {
  int i = blockIdx.x * 256 + threadIdx.x;
  if (i >= n4) return;
  fv4 v = ((const fv4*)x)[i];
  int e = i * 4;
#pragma unroll
  for (int j = 0; j < 4; ++j) v[j] += fc[(e + j) / 49];
  ((fv4*)out)[i] = v;
}

// ---------------------------------------------------------------- launch
extern "C" void kernel_launch(void* const* d_in, const int* in_sizes, int n_in,
                              void* d_out, int out_size, void* d_ws,
                              size_t ws_size, hipStream_t stream) {
  (void)in_sizes; (void)n_in; (void)out_size; (void)ws_size;
  const float* x = (const float*)d_in[0];
  const float* xc = (const float*)d_in[1];
  const int* nvp = (const int*)d_in[2];
  const float* qW = (const float*)d_in[3];
  const float* qB = (const float*)d_in[4];
  const float* qG = (const float*)d_in[5];
  const float* qBe = (const float*)d_in[6];
  const float* qM = (const float*)d_in[7];
  const float* qV = (const float*)d_in[8];
  const float* kW = (const float*)d_in[9];
  const float* kB = (const float*)d_in[10];
  const float* kG = (const float*)d_in[11];
  const float* kBe = (const float*)d_in[12];
  const float* kM = (const float*)d_in[13];
  const float* kV = (const float*)d_in[14];
  const float* vW = (const float*)d_in[15];
  const float* vB = (const float*)d_in[16];
  const float* vG = (const float*)d_in[17];
  const float* vBe = (const float*)d_in[18];
  const float* vM = (const float*)d_in[19];
  const float* vV = (const float*)d_in[20];
  const float* fW = (const float*)d_in[21];
  const float* fB = (const float*)d_in[22];
  const float* fG = (const float*)d_in[23];
  const float* fBe = (const float*)d_in[24];
  const float* fM = (const float*)d_in[25];
  const float* fV = (const float*)d_in[26];
  float* out = (float*)d_out;

  const int NRq = 512;    // B*n
  const int NRc = 16384;  // B*m
  const int Dd = 1024, Cc = 2048, D1 = 2048, D2 = 2048, Mm = 2048;

  char* p = (char*)d_ws;
  auto take = [&](size_t bytes) -> char* {
    char* r = p;
    p += (bytes + 255) & ~(size_t)255;
    return r;
  };
  f16* xch = (f16*)take((size_t)NRc * Cc * 2);
  f16* kh = (f16*)take((size_t)NRc * D1 * 2);
  f16* kl = (f16*)take((size_t)NRc * D1 * 2);
  f16* vh = (f16*)take((size_t)NRc * D2 * 2);
  f16* vT = (f16*)take((size_t)NRc * D2 * 2);
  f16* qWh = (f16*)take((size_t)D1 * Dd * 2);
  f16* qWl = (f16*)take((size_t)D1 * Dd * 2);
  f16* kWh = (f16*)take((size_t)D1 * Cc * 2);
  f16* kWl = (f16*)take((size_t)D1 * Cc * 2);
  f16* vWh = (f16*)take((size_t)D2 * Cc * 2);
  f16* fWh = (f16*)take((size_t)Dd * D2 * 2);
  f16* Aph = (f16*)take((size_t)NRq * Dd * 2);
  f16* qh = (f16*)take((size_t)NRq * D1 * 2);
  f16* ql = (f16*)take((size_t)NRq * D1 * 2);
  float* qn2 = (float*)take((size_t)NRq * 4);
  float* kn2 = (float*)take((size_t)NRc * 4);
  float* vn2 = (float*)take((size_t)NRc * 4);
  float* raw = (float*)take((size_t)NRq * Mm * 4);
  f16* wgt = (f16*)take((size_t)NRq * Mm * 2);
  f16* wvh = (f16*)take((size_t)NRq * D2 * 2);
  float* fctx = (float*)take((size_t)NRq * Dd * 4);

  // conversions to fp16 (weights hi/lo; activations hi only)
  cvt_hi_kernel<<<dim3((NRc * Cc / 4 + 255) / 256), 256, 0, stream>>>(
      xc, xch, NRc * Cc / 4);
  cvt_hilo_kernel<<<dim3((D1 * Dd / 4 + 255) / 256), 256, 0, stream>>>(
      qW, qWh, qWl, D1 * Dd / 4);
  cvt_hilo_kernel<<<dim3((D1 * Cc / 4 + 255) / 256), 256, 0, stream>>>(
      kW, kWh, kWl, D1 * Cc / 4);
  cvt_hi_kernel<<<dim3((D2 * Cc / 4 + 255) / 256), 256, 0, stream>>>(
      vW, vWh, D2 * Cc / 4);
  cvt_hi_kernel<<<dim3((Dd * D2 / 4 + 255) / 256), 256, 0, stream>>>(
      fW, fWh, Dd * D2 / 4);
  pool_kernel<<<dim3(512), 256, 0, stream>>>(x, Aph);

  hipMemsetAsync(qn2, 0, (size_t)NRq * 4, stream);
  hipMemsetAsync(kn2, 0, (size_t)NRc * 4, stream);
  hipMemsetAsync(vn2, 0, (size_t)NRc * 4, stream);

  // Q: [512,1024] x [2048,1024]^T, 2-pass (W-side hi/lo) -> hi/lo + norm2
  gemm_kernel<128, 128, 1, 2, EPI_HILO_NORM>
      <<<dim3(D1 / 128, NRq / 128, 1), 256, 0, stream>>>(
          Aph, nullptr, qWh, qWl, NRq, D1, Dd, 0, 0, 0, nullptr, qh, ql, qB,
          qG, qBe, qM, qV, qn2);
  // K: [16384,2048] x [2048,2048]^T, 2-pass (W-side hi/lo)
  gemm_kernel<128, 128, 1, 2, EPI_HILO_NORM>
      <<<dim3(D1 / 128, NRc / 128, 1), 256, 0, stream>>>(
          xch, nullptr, kWh, kWl, NRc, D1, Cc, 0, 0, 0, nullptr, kh, kl, kB,
          kG, kBe, kM, kV, kn2);
  // V: single-pass fp16
  gemm_kernel<128, 128, 1, 1, EPI_HALF_NORM>
      <<<dim3(D2 / 128, NRc / 128, 1), 256, 0, stream>>>(
          xch, nullptr, vWh, nullptr, NRc, D2, Cc, 0, 0, 0, nullptr, vh,
          nullptr, vB, vG, vBe, vM, vV, vn2);
  // values -> values^T per batch (for wv GEMM B-operand)
  transpose_kernel<<<dim3(32, 32, 8), 256, 0, stream>>>(vh, vT);
  // sim (batched): q[64,2048] x k[2048,2048]^T, 3-pass -> raw fp32
  gemm_kernel<64, 128, 2, 2, EPI_RAW><<<dim3(Mm / 128, 1, 8), 256, 0, stream>>>(
      qh, ql, kh, kl, 64, Mm, D1, (long long)64 * D1, (long long)Mm * D1,
      (long long)64 * Mm, raw, nullptr, nullptr, nullptr, nullptr, nullptr,
      nullptr, nullptr, nullptr);
  softmax_kernel<<<dim3(64, 8), 256, 0, stream>>>(raw, qn2, kn2, vn2, nvp, wgt);
  // wv (batched): wgt[64,2048] x vT[2048,2048]^T -> fp16
  gemm_kernel<64, 128, 1, 1, EPI_HALF><<<dim3(D2 / 128, 1, 8), 256, 0, stream>>>(
      wgt, nullptr, vT, nullptr, 64, D2, Mm, (long long)64 * Mm,
      (long long)D2 * Mm, (long long)64 * D2, nullptr, wvh, nullptr, nullptr,
      nullptr, nullptr, nullptr, nullptr, nullptr);
  // f: [512,2048] x [1024,2048]^T -> BN/ReLU -> fp32
  gemm_kernel<128, 128, 1, 1, EPI_BN_F32>
      <<<dim3(Dd / 128, NRq / 128, 1), 256, 0, stream>>>(
          wvh, nullptr, fWh, nullptr, NRq, Dd, D2, 0, 0, 0, fctx, nullptr,
          nullptr, fB, fG, fBe, fM, fV, nullptr);
  // out = x + f_context broadcast
  add_kernel<<<dim3(25690112 / 4 / 256), 256, 0, stream>>>(x, fctx, out,
                                                           25690112 / 4);
}